// Round 8
// baseline (228.689 us; speedup 1.0000x reference)
//
#include <hip/hip_runtime.h>

#define N_NODES 50000
#define N_EDGES 800000
#define D 64
#define N_LAYERS 3
#define N_GRAPHS 512

#define NB 196            // buckets = ceil(50000/256); bucket = dst >> 8
#define BCAP 5120         // per-bucket capacity: mean 4082, sigma 64 -> 16 sigma
#define P3_CHUNK 2048
#define N_P3_WG ((N_EDGES + P3_CHUNK - 1) / P3_CHUNK)  // 391

// ---- CSR build: two-level counting sort ---------------------------------

__global__ __launch_bounds__(256) void bucket_scatter_kernel(
    const int* __restrict__ src, const int* __restrict__ dst,
    int* __restrict__ bucket_fill, int* __restrict__ bucketArr, int nE) {
    __shared__ int hist[NB], base[NB], cur[NB];
    int tid = threadIdx.x;
    if (tid < NB) hist[tid] = 0;
    __syncthreads();
    int s8[8], d8[8];
    bool v8[8];
    int ebase = blockIdx.x * P3_CHUNK + tid;
    #pragma unroll
    for (int i = 0; i < 8; ++i) {
        int e = ebase + i * 256;
        v8[i] = (e < nE);
        if (v8[i]) {
            s8[i] = src[e];
            d8[i] = dst[e];
            atomicAdd(&hist[d8[i] >> 8], 1);
        }
    }
    __syncthreads();
    if (tid < NB) {
        base[tid] = atomicAdd(&bucket_fill[tid], hist[tid]);
        cur[tid] = 0;
    }
    __syncthreads();
    #pragma unroll
    for (int i = 0; i < 8; ++i) {
        if (v8[i]) {
            int b = d8[i] >> 8;
            int r = atomicAdd(&cur[b], 1);
            int pos = base[b] + r;
            if (pos < BCAP)
                bucketArr[b * BCAP + pos] = (s8[i] & 0xFFFF) | ((d8[i] & 0xFF) << 16);
        }
    }
}

__global__ __launch_bounds__(256) void bucket_scan_kernel(
    const int* __restrict__ bucket_fill, int* __restrict__ bucket_base,
    int* __restrict__ offsets) {
    __shared__ int sm[256];
    int tid = threadIdx.x;
    int own = (tid < NB) ? bucket_fill[tid] : 0;
    sm[tid] = own;
    __syncthreads();
    for (int off = 1; off < 256; off <<= 1) {
        int v = (tid >= off) ? sm[tid - off] : 0;
        __syncthreads();
        sm[tid] += v;
        __syncthreads();
    }
    if (tid < NB) bucket_base[tid] = sm[tid] - own;  // exclusive
    if (tid == 0) offsets[N_NODES] = N_EDGES;
}

__global__ __launch_bounds__(256) void bucket_csr_kernel(
    const int* __restrict__ bucket_fill, const int* __restrict__ bucket_base,
    const int* __restrict__ bucketArr,
    int* __restrict__ offsets, int* __restrict__ csr_src,
    float* __restrict__ dinv) {
    __shared__ int ldeg[256], lsc[256], lcur[256];
    int b = blockIdx.x;
    int tid = threadIdx.x;
    int cnt = min(bucket_fill[b], BCAP);
    int cbase = bucket_base[b];
    const int* seg = bucketArr + b * BCAP;
    ldeg[tid] = 0;
    __syncthreads();
    for (int e = tid; e < cnt; e += 256)
        atomicAdd(&ldeg[(seg[e] >> 16) & 0xFF], 1);
    __syncthreads();
    int own = ldeg[tid];
    lsc[tid] = own;
    __syncthreads();
    for (int off = 1; off < 256; off <<= 1) {
        int v = (tid >= off) ? lsc[tid - off] : 0;
        __syncthreads();
        lsc[tid] += v;
        __syncthreads();
    }
    int excl = lsc[tid] - own;
    int node = b * 256 + tid;
    if (node < N_NODES) {
        offsets[node] = cbase + excl;
        dinv[node] = rsqrtf((float)own + 1.0f);
    }
    lcur[tid] = cbase + excl;
    __syncthreads();
    for (int e = tid; e < cnt; e += 256) {
        int p = seg[e];
        int pos = atomicAdd(&lcur[(p >> 16) & 0xFF], 1);
        csr_src[pos] = p & 0xFFFF;
    }
}

// ---- graph boundaries from sorted batch ----------------------------------

__global__ __launch_bounds__(256) void gbounds_kernel(
    const int* __restrict__ batch, int* __restrict__ gstart, int nN) {
    int i = blockIdx.x * 256 + threadIdx.x;
    if (i >= nN) return;
    int b = batch[i];
    int prev = (i == 0) ? -1 : batch[i - 1];
    for (int g = prev + 1; g <= b; ++g) gstart[g] = i;
    if (i == nN - 1) {
        for (int g = b + 1; g <= N_GRAPHS; ++g) gstart[g] = nN;
    }
}

// ---- per-layer kernels --------------------------------------------------

#define GROWS 64
#define LPAD 68
__global__ __launch_bounds__(256) void gemm_kernel(
    const float* __restrict__ h, const float* __restrict__ W,
    const float* __restrict__ dinv, float* __restrict__ hWs, int nN) {
    __shared__ float hs[GROWS][LPAD];
    __shared__ float Wl[D][LPAD];
    int tid = threadIdx.x;
    int row0 = blockIdx.x * GROWS;
    #pragma unroll
    for (int i = 0; i < 4; ++i) {
        int idx4 = tid + i * 256;
        int r = idx4 >> 4;
        int c4 = (idx4 & 15) << 2;
        *(float4*)&Wl[r][c4] = *(const float4*)&W[r * D + c4];
        float4 hv = make_float4(0.f, 0.f, 0.f, 0.f);
        int gr = row0 + r;
        if (gr < nN) hv = *(const float4*)&h[(size_t)gr * D + c4];
        *(float4*)&hs[r][c4] = hv;
    }
    __syncthreads();
    int r0 = (tid >> 4) << 2;
    int c0 = (tid & 15) << 2;
    float acc[4][4];
    #pragma unroll
    for (int i = 0; i < 4; ++i)
        #pragma unroll
        for (int j = 0; j < 4; ++j) acc[i][j] = 0.f;
    #pragma unroll
    for (int kk = 0; kk < D; kk += 4) {
        float4 a0 = *(float4*)&hs[r0 + 0][kk];
        float4 a1 = *(float4*)&hs[r0 + 1][kk];
        float4 a2 = *(float4*)&hs[r0 + 2][kk];
        float4 a3 = *(float4*)&hs[r0 + 3][kk];
        float4 w0 = *(float4*)&Wl[kk + 0][c0];
        float4 w1 = *(float4*)&Wl[kk + 1][c0];
        float4 w2 = *(float4*)&Wl[kk + 2][c0];
        float4 w3 = *(float4*)&Wl[kk + 3][c0];
        float* w0p = &w0.x; float* w1p = &w1.x; float* w2p = &w2.x; float* w3p = &w3.x;
        float4 av[4] = {a0, a1, a2, a3};
        #pragma unroll
        for (int i = 0; i < 4; ++i) {
            #pragma unroll
            for (int j = 0; j < 4; ++j) {
                acc[i][j] += av[i].x * w0p[j] + av[i].y * w1p[j]
                           + av[i].z * w2p[j] + av[i].w * w3p[j];
            }
        }
    }
    #pragma unroll
    for (int i = 0; i < 4; ++i) {
        int gr = row0 + r0 + i;
        if (gr < nN) {
            float s = dinv[gr];
            float4 o = make_float4(acc[i][0] * s, acc[i][1] * s,
                                   acc[i][2] * s, acc[i][3] * s);
            *(float4*)&hWs[(size_t)gr * D + c0] = o;
        }
    }
}

// h_out[t] = dinv[t] * (hWs[t] + sum_{s in N(t)} hWs[s]) + b
// one wave per dst node; 16 lanes per edge (float4 gather);
// 4-deep unroll -> 16 edges (4 KB) in flight per wave
__global__ __launch_bounds__(256) void agg_kernel(
    const int* __restrict__ offsets, const int* __restrict__ csr_src,
    const float* __restrict__ hWs, const float* __restrict__ dinv,
    const float* __restrict__ b, float* __restrict__ hout, int nN) {
    int wave = threadIdx.x >> 6;
    int lane = threadIdx.x & 63;
    int t = blockIdx.x * 4 + wave;
    if (t >= nN) return;
    int beg = offsets[t];
    int end = offsets[t + 1];
    int grp = lane >> 4;          // edge slot 0..3
    int q4  = (lane & 15) << 2;   // dim offset
    float4 a0 = make_float4(0.f, 0.f, 0.f, 0.f);
    float4 a1 = make_float4(0.f, 0.f, 0.f, 0.f);
    float4 a2 = make_float4(0.f, 0.f, 0.f, 0.f);
    float4 a3 = make_float4(0.f, 0.f, 0.f, 0.f);
    int e = beg + grp;
    for (; e + 12 < end; e += 16) {
        int s0 = csr_src[e];
        int s1 = csr_src[e + 4];
        int s2 = csr_src[e + 8];
        int s3 = csr_src[e + 12];
        float4 v0 = *(const float4*)&hWs[(size_t)s0 * D + q4];
        float4 v1 = *(const float4*)&hWs[(size_t)s1 * D + q4];
        float4 v2 = *(const float4*)&hWs[(size_t)s2 * D + q4];
        float4 v3 = *(const float4*)&hWs[(size_t)s3 * D + q4];
        a0.x += v0.x; a0.y += v0.y; a0.z += v0.z; a0.w += v0.w;
        a1.x += v1.x; a1.y += v1.y; a1.z += v1.z; a1.w += v1.w;
        a2.x += v2.x; a2.y += v2.y; a2.z += v2.z; a2.w += v2.w;
        a3.x += v3.x; a3.y += v3.y; a3.z += v3.z; a3.w += v3.w;
    }
    for (; e < end; e += 4) {
        int s0 = csr_src[e];
        float4 v0 = *(const float4*)&hWs[(size_t)s0 * D + q4];
        a0.x += v0.x; a0.y += v0.y; a0.z += v0.z; a0.w += v0.w;
    }
    float4 acc = make_float4(a0.x + a1.x + a2.x + a3.x,
                             a0.y + a1.y + a2.y + a3.y,
                             a0.z + a1.z + a2.z + a3.z,
                             a0.w + a1.w + a2.w + a3.w);
    // fold the 4 edge-slots: lanes {l, l^16, l^32, l^48} share dim-quad
    #pragma unroll
    for (int m = 16; m < 64; m <<= 1) {
        acc.x += __shfl_xor(acc.x, m);
        acc.y += __shfl_xor(acc.y, m);
        acc.z += __shfl_xor(acc.z, m);
        acc.w += __shfl_xor(acc.w, m);
    }
    if (grp == 0) {
        float4 self = *(const float4*)&hWs[(size_t)t * D + q4];
        float dt = dinv[t];
        float4 bb = *(const float4*)&b[q4];
        float4 o;
        o.x = (acc.x + self.x) * dt + bb.x;
        o.y = (acc.y + self.y) * dt + bb.y;
        o.z = (acc.z + self.z) * dt + bb.z;
        o.w = (acc.w + self.w) * dt + bb.w;
        *(float4*)&hout[(size_t)t * D + q4] = o;
    }
}

// ---- pooling: one block per graph, 4 waves, LDS reduce -------------------

__global__ __launch_bounds__(256) void pool_kernel(
    const float* __restrict__ h, const int* __restrict__ gstart,
    float* __restrict__ out) {
    __shared__ float sm[4][D];
    int g = blockIdx.x;
    int wave = threadIdx.x >> 6;
    int lane = threadIdx.x & 63;
    int beg = gstart[g];
    int end = gstart[g + 1];
    float acc = 0.f;
    int n = beg + wave;
    for (; n + 12 < end; n += 16) {
        float a0 = h[(size_t)(n)      * D + lane];
        float a1 = h[(size_t)(n + 4)  * D + lane];
        float a2 = h[(size_t)(n + 8)  * D + lane];
        float a3 = h[(size_t)(n + 12) * D + lane];
        acc += a0 + a1 + a2 + a3;
    }
    for (; n < end; n += 4)
        acc += h[(size_t)n * D + lane];
    sm[wave][lane] = acc;
    __syncthreads();
    if (wave == 0) {
        float s = sm[0][lane] + sm[1][lane] + sm[2][lane] + sm[3][lane];
        float cnt = (float)(end - beg);
        out[g * D + lane] = s / fmaxf(cnt, 1.0f);
    }
}

// ---- launch --------------------------------------------------------------

#define WS_ALIGN(p) ((char*)(((size_t)(p) + 255) & ~(size_t)255))

extern "C" void kernel_launch(void* const* d_in, const int* in_sizes, int n_in,
                              void* d_out, int out_size, void* d_ws, size_t ws_size,
                              hipStream_t stream) {
    const float* x     = (const float*)d_in[0];
    const float* Ws    = (const float*)d_in[1];
    const float* bs    = (const float*)d_in[2];
    const int*   edge  = (const int*)d_in[3];
    const int*   batch = (const int*)d_in[4];
    const int* src = edge;            // edge_index[0]
    const int* dst = edge + N_EDGES;  // edge_index[1]
    float* out = (float*)d_out;

    char* p = (char*)d_ws;
    int* offsets     = (int*)p;      p = WS_ALIGN(p + sizeof(int) * (N_NODES + 1));
    int* csr_src     = (int*)p;      p = WS_ALIGN(p + sizeof(int) * N_EDGES);
    int* bucket_fill = (int*)p;      p = WS_ALIGN(p + sizeof(int) * NB);
    int* bucket_base = (int*)p;      p = WS_ALIGN(p + sizeof(int) * NB);
    int* gstart      = (int*)p;      p = WS_ALIGN(p + sizeof(int) * (N_GRAPHS + 1));
    float* dinv      = (float*)p;    p = WS_ALIGN(p + sizeof(float) * N_NODES);
    float* B1        = (float*)p;    p = WS_ALIGN(p + sizeof(float) * (size_t)N_NODES * D);
    float* B2        = (float*)p;
    // bucketArr (NB*BCAP ints = 4.0 MB) overlays B2: dead before first agg write
    int* bucketArr = (int*)B2;

    hipMemsetAsync(bucket_fill, 0, NB * sizeof(int), stream);

    bucket_scatter_kernel<<<N_P3_WG, 256, 0, stream>>>(src, dst, bucket_fill, bucketArr, N_EDGES);
    bucket_scan_kernel<<<1, 256, 0, stream>>>(bucket_fill, bucket_base, offsets);
    bucket_csr_kernel<<<NB, 256, 0, stream>>>(bucket_fill, bucket_base, bucketArr,
                                              offsets, csr_src, dinv);
    gbounds_kernel<<<(N_NODES + 255) / 256, 256, 0, stream>>>(batch, gstart, N_NODES);

    const float* h = x;
    for (int l = 0; l < N_LAYERS; ++l) {
        gemm_kernel<<<(N_NODES + GROWS - 1) / GROWS, 256, 0, stream>>>(
            h, Ws + (size_t)l * D * D, dinv, B1, N_NODES);
        agg_kernel<<<(N_NODES + 3) / 4, 256, 0, stream>>>(
            offsets, csr_src, B1, dinv, bs + (size_t)l * D, B2, N_NODES);
        h = B2;
    }

    pool_kernel<<<N_GRAPHS, 256, 0, stream>>>(h, gstart, out);
}